// Round 1
// baseline (840.690 us; speedup 1.0000x reference)
//
#include <hip/hip_runtime.h>
#include <math.h>

// Problem geometry
// B=4, L=4096, H=16, NBk=64, D=1024, HID=128, NS=1024, TOKENS=16384
// out layout: [theta_hat 16777216 | Pi 1024 | K 16777216 | R 16777216]
static constexpr size_t OUT_THETA = 0;
static constexpr size_t OUT_PI    = 16777216;
static constexpr size_t OUT_K     = 16778240;
static constexpr size_t OUT_R     = 33555456;

#define PI_F 3.14159265358979323846f

// ---------------------------------------------------------------------------
// K1: H = gelu_exact(X @ W1 + b1) for both heads.
// X: (16384,1024)  W: (1024,128) each head.  H: (16384,256), cols [0,128)=r head,
// [128,256)=m head.  BM=64, BN=64, BK=16, 256 threads, 4x4 microtile.
// grid: (256 token tiles, 4 n tiles)  ntile 0,1 -> r head; 2,3 -> m head.
// ---------------------------------------------------------------------------
__global__ __launch_bounds__(256) void k_gemm1(
    const float* __restrict__ X,
    const float* __restrict__ Wr1, const float* __restrict__ br1,
    const float* __restrict__ Wm1, const float* __restrict__ bm1,
    float* __restrict__ Hout)
{
    __shared__ float As[16][68];   // [k][m], padded
    __shared__ float Bs[16][64];   // [k][n]
    const int tt = blockIdx.x;
    const int nt = blockIdx.y;
    const float* __restrict__ W    = (nt < 2) ? Wr1 : Wm1;
    const float* __restrict__ bias = (nt < 2) ? br1 : bm1;
    const int col0 = (nt & 1) * 64;
    const int m0 = tt * 64;
    const int tid = threadIdx.x;
    const int tm = tid >> 4, tn = tid & 15;
    const int lm = tid >> 2, lk4 = (tid & 3) << 2;     // A loader: one float4
    const int bkr = tid >> 4, bn4 = (tid & 15) << 2;   // B loader: one float4

    float acc[4][4] = {};
    for (int k0 = 0; k0 < 1024; k0 += 16) {
        float4 av = *(const float4*)(X + (size_t)(m0 + lm) * 1024 + k0 + lk4);
        float4 bv = *(const float4*)(W + (size_t)(k0 + bkr) * 128 + col0 + bn4);
        __syncthreads();
        As[lk4 + 0][lm] = av.x; As[lk4 + 1][lm] = av.y;
        As[lk4 + 2][lm] = av.z; As[lk4 + 3][lm] = av.w;
        *(float4*)&Bs[bkr][bn4] = bv;
        __syncthreads();
#pragma unroll
        for (int kk = 0; kk < 16; ++kk) {
            float a[4], b[4];
#pragma unroll
            for (int i = 0; i < 4; ++i) a[i] = As[kk][tm * 4 + i];
#pragma unroll
            for (int j = 0; j < 4; ++j) b[j] = Bs[kk][tn * 4 + j];
#pragma unroll
            for (int i = 0; i < 4; ++i)
#pragma unroll
                for (int j = 0; j < 4; ++j)
                    acc[i][j] = fmaf(a[i], b[j], acc[i][j]);
        }
    }
#pragma unroll
    for (int i = 0; i < 4; ++i) {
        float4 hv; float* hp = (float*)&hv;
#pragma unroll
        for (int j = 0; j < 4; ++j) {
            float x = acc[i][j] + bias[col0 + tn * 4 + j];
            hp[j] = 0.5f * x * (1.0f + erff(x * 0.70710678118654752f)); // exact GELU
        }
        *(float4*)(Hout + (size_t)(m0 + tm * 4 + i) * 256 + nt * 64 + tn * 4) = hv;
    }
}

// ---------------------------------------------------------------------------
// K2: second linear for both heads + full elementwise tail + chunk-local scan.
// Block = (token tile tt in [0,256): b=tt>>6, chunk c=tt&63) x (j tile jt in [0,16)).
// Computes accr = Hr@Wr2, accm = Hm@Wm2 (K=128), then:
//   R = exp(clip(accr+br2,-5,5)); Kg = Pi/max(Pi+R,1e-8); alpha = 1-Kg
//   z = pi*tanh(accm+bm2); nu = atan2(sin(z-theta),cos(z-theta)); u = Kg*nu
// Writes R,K to d_out, u into the theta_hat slot (scratch), and the chunk
// aggregates A = prod(alpha), U = local scan end value to ws.
// ---------------------------------------------------------------------------
__global__ __launch_bounds__(256) void k_head2(
    const float* __restrict__ Hin,
    const float* __restrict__ Wr2, const float* __restrict__ br2,
    const float* __restrict__ Wm2, const float* __restrict__ bm2,
    const float* __restrict__ log_Pi, const float* __restrict__ theta,
    float* __restrict__ out, float* __restrict__ Aws, float* __restrict__ Uws)
{
    __shared__ union {
        struct { float Ar[16][68]; float Am[16][68]; float Br[16][64]; float Bm[16][64]; } g;
        struct { float al[64][65]; float ul[64][65]; } s;   // [local j][local t]
    } sm;
    const int tt = blockIdx.x;
    const int jt = blockIdx.y;
    const int n0 = jt * 64, m0 = tt * 64;
    const int tid = threadIdx.x;
    const int tm = tid >> 4, tn = tid & 15;
    const int lm = tid >> 2, lk4 = (tid & 3) << 2;
    const int bkr = tid >> 4, bn4 = (tid & 15) << 2;

    float accr[4][4] = {}, accm[4][4] = {};
    for (int k0 = 0; k0 < 128; k0 += 16) {
        float4 avr = *(const float4*)(Hin + (size_t)(m0 + lm) * 256 + 0   + k0 + lk4);
        float4 avm = *(const float4*)(Hin + (size_t)(m0 + lm) * 256 + 128 + k0 + lk4);
        float4 bvr = *(const float4*)(Wr2 + (size_t)(k0 + bkr) * 1024 + n0 + bn4);
        float4 bvm = *(const float4*)(Wm2 + (size_t)(k0 + bkr) * 1024 + n0 + bn4);
        __syncthreads();
        sm.g.Ar[lk4 + 0][lm] = avr.x; sm.g.Ar[lk4 + 1][lm] = avr.y;
        sm.g.Ar[lk4 + 2][lm] = avr.z; sm.g.Ar[lk4 + 3][lm] = avr.w;
        sm.g.Am[lk4 + 0][lm] = avm.x; sm.g.Am[lk4 + 1][lm] = avm.y;
        sm.g.Am[lk4 + 2][lm] = avm.z; sm.g.Am[lk4 + 3][lm] = avm.w;
        *(float4*)&sm.g.Br[bkr][bn4] = bvr;
        *(float4*)&sm.g.Bm[bkr][bn4] = bvm;
        __syncthreads();
#pragma unroll
        for (int kk = 0; kk < 16; ++kk) {
            float ar[4], am[4], br_[4], bm_[4];
#pragma unroll
            for (int i = 0; i < 4; ++i) { ar[i] = sm.g.Ar[kk][tm * 4 + i]; am[i] = sm.g.Am[kk][tm * 4 + i]; }
#pragma unroll
            for (int j = 0; j < 4; ++j) { br_[j] = sm.g.Br[kk][tn * 4 + j]; bm_[j] = sm.g.Bm[kk][tn * 4 + j]; }
#pragma unroll
            for (int i = 0; i < 4; ++i)
#pragma unroll
                for (int j = 0; j < 4; ++j) {
                    accr[i][j] = fmaf(ar[i], br_[j], accr[i][j]);
                    accm[i][j] = fmaf(am[i], bm_[j], accm[i][j]);
                }
        }
    }
    __syncthreads();   // GEMM LDS dead; union reused for scan staging below

    float Pis[4], b2r[4], b2m[4];
#pragma unroll
    for (int j = 0; j < 4; ++j) {
        Pis[j] = expf(log_Pi[n0 + tn * 4 + j]);
        b2r[j] = br2[n0 + tn * 4 + j];
        b2m[j] = bm2[n0 + tn * 4 + j];
    }
#pragma unroll
    for (int i = 0; i < 4; ++i) {
        const int m = tm * 4 + i;
        const size_t idx = (size_t)(m0 + m) * 1024 + n0 + tn * 4;
        float4 th4 = *(const float4*)(theta + idx);
        const float* tp = (const float*)&th4;
        float4 Kv, Rv, Uv;
        float* Kp = (float*)&Kv; float* Rp = (float*)&Rv; float* Up = (float*)&Uv;
#pragma unroll
        for (int j = 0; j < 4; ++j) {
            float lr = accr[i][j] + b2r[j];
            lr = fminf(fmaxf(lr, -5.0f), 5.0f);
            float R  = expf(lr);
            float Kg = Pis[j] / fmaxf(Pis[j] + R, 1e-8f);
            float zp = accm[i][j] + b2m[j];
            float z  = PI_F * tanhf(zp);
            float diff = z - tp[j];
            float nu = atan2f(sinf(diff), cosf(diff));  // wrapped innovation
            float u  = Kg * nu;
            Kp[j] = Kg; Rp[j] = R; Up[j] = u;
            sm.s.al[tn * 4 + j][m] = 1.0f - Kg;
            sm.s.ul[tn * 4 + j][m] = u;
        }
        *(float4*)(out + OUT_K + idx)     = Kv;
        *(float4*)(out + OUT_R + idx)     = Rv;
        *(float4*)(out + OUT_THETA + idx) = Uv;  // u stashed in theta slot
    }
    __syncthreads();
    if (tid < 64) {   // chunk-local affine scan along the 64 tokens
        const int j = tid;
        float ap = 1.0f, d = 0.0f;
#pragma unroll 8
        for (int t = 0; t < 64; ++t) {
            float a = sm.s.al[j][t];
            float u = sm.s.ul[j][t];
            d = fmaf(a, d, u);
            ap *= a;
        }
        Aws[(size_t)tt * 1024 + n0 + j] = ap;
        Uws[(size_t)tt * 1024 + n0 + j] = d;
    }
}

// ---------------------------------------------------------------------------
// K3: serial scan over the 64 chunk aggregates per sequence -> carry into each chunk.
// grid 16 blocks x 256 threads: block = (b, jgroup of 256).
// ---------------------------------------------------------------------------
__global__ __launch_bounds__(256) void k_carry(
    const float* __restrict__ Aws, const float* __restrict__ Uws, float* __restrict__ Cws)
{
    const int b = blockIdx.x >> 2;
    const int j = (blockIdx.x & 3) * 256 + threadIdx.x;
    float carry = 0.0f;
    for (int c = 0; c < 64; ++c) {
        const size_t off = (size_t)(b * 64 + c) * 1024 + j;
        float a = Aws[off], u = Uws[off];
        Cws[off] = carry;               // carry entering chunk c
        carry = fmaf(a, carry, u);
    }
}

// ---------------------------------------------------------------------------
// K4: apply — rescan each chunk seeded with its carry; theta_hat = theta + d.
// Reads u from the theta slot and overwrites it in place.
// grid 1024 blocks x 256 threads: block = (b, c, jgroup).
// ---------------------------------------------------------------------------
__global__ __launch_bounds__(256) void k_apply(
    const float* __restrict__ theta, const float* __restrict__ Cws, float* __restrict__ out)
{
    const int bid = blockIdx.x;
    const int jg = bid & 3;
    const int c  = (bid >> 2) & 63;
    const int b  = bid >> 8;
    const int j  = jg * 256 + threadIdx.x;
    float d = Cws[(size_t)(b * 64 + c) * 1024 + j];
    size_t idx = (size_t)(b * 4096 + c * 64) * 1024 + j;
    const float* __restrict__ Kbase = out + OUT_K;
#pragma unroll 4
    for (int i = 0; i < 64; ++i) {
        float Kg = Kbase[idx];
        float u  = out[idx];
        d = fmaf(1.0f - Kg, d, u);
        out[idx] = theta[idx] + d;
        idx += 1024;
    }
}

__global__ void k_pi(const float* __restrict__ log_Pi, float* __restrict__ out)
{
    int j = blockIdx.x * 256 + threadIdx.x;
    if (j < 1024) out[OUT_PI + j] = expf(log_Pi[j]);
}

extern "C" void kernel_launch(void* const* d_in, const int* in_sizes, int n_in,
                              void* d_out, int out_size, void* d_ws, size_t ws_size,
                              hipStream_t stream)
{
    const float* theta = (const float*)d_in[0];
    const float* x     = (const float*)d_in[1];
    const float* logPi = (const float*)d_in[2];
    const float* Wr1   = (const float*)d_in[3];
    const float* br1   = (const float*)d_in[4];
    const float* Wr2   = (const float*)d_in[5];
    const float* br2   = (const float*)d_in[6];
    const float* Wm1   = (const float*)d_in[7];
    const float* bm1   = (const float*)d_in[8];
    const float* Wm2   = (const float*)d_in[9];
    const float* bm2   = (const float*)d_in[10];
    float* out = (float*)d_out;

    float* Hws = (float*)d_ws;                       // 16384*256 = 4,194,304 f
    float* Aws = Hws + (size_t)16384 * 256;          // 262,144 f
    float* Uws = Aws + 262144;                       // 262,144 f
    float* Cws = Uws + 262144;                       // 262,144 f   (~20 MB total)

    k_gemm1<<<dim3(256, 4), 256, 0, stream>>>(x, Wr1, br1, Wm1, bm1, Hws);
    k_pi<<<4, 256, 0, stream>>>(logPi, out);
    k_head2<<<dim3(256, 16), 256, 0, stream>>>(Hws, Wr2, br2, Wm2, bm2, logPi, theta, out, Aws, Uws);
    k_carry<<<16, 256, 0, stream>>>(Aws, Uws, Cws);
    k_apply<<<1024, 256, 0, stream>>>(theta, Cws, out);
}